// Round 9
// baseline (239.254 us; speedup 1.0000x reference)
//
#include <hip/hip_runtime.h>
#include <math.h>

#define KB 16

// Native clang vector type — required for __builtin_nontemporal_load/store.
typedef float vf4 __attribute__((ext_vector_type(4)));

// Per-element core. Faithful fp32 op order vs reference (__f*_rn blocks FMA
// contraction; rintf == round-half-even == jnp.round). Division by alpha is
// multiply by precomputed 1/alpha — bit-exact for pow2 alpha (bench: 1.0).
// Table holds pv[m] = __fmul_rn(alpha, zval[m]) — same operands/op as the
// reference's final alpha-multiply -> bit-identical (R4/R5/R6/R8: absmax 0.0);
// high path alpha*1.0 == alpha exactly.
__device__ __forceinline__ float lcq_core(float xv, float alpha, float rcp_alpha,
                                          const float2* __restrict__ s_gb,
                                          const float* __restrict__ s_pv)
{
    float a   = fabsf(xv);
    float xt  = __fmul_rn(a, rcp_alpha);            // x_tmp = |x|/alpha
    float t16 = __fmul_rn(xt, 16.0f);               // exact pow2 scale
    float jf  = fminf(t16, 15.0f);
    int   j   = (int)jf;                            // searchsorted(dst,·,right)-1
    float2 gb = s_gb[j];                            // ds_read_b64, conflict-free
    float dj  = __fmul_rn(floorf(jf), 0.0625f);     // dst[j] = j/16, exact
    float y   = __fadd_rn(__fmul_rn(gb.x, __fsub_rn(xt, dj)), gb.y);
    float t   = rintf(__fmul_rn(y, 15.0f));         // m = round(y*s), half-even; t>=0
    int   m   = (int)fminf(t, 15.0f);
    float r   = (a < alpha) ? s_pv[m] : alpha;      // flag select, alpha pre-folded
    return copysignf(r, xv);                        // x==0 -> 0 (pv[0]==0)
}

// ROUND 9: push the R8-proven MLP lever (the only lever with a positive
// response in 8 rounds of A/B) one more doubling. R8 (8 loads, ~76 VGPR)
// already crossed the 64-VGPR occupancy cliff and still won — ILP fully
// compensated the halved TLP tier. 16 loads stays in the SAME 65-128 VGPR
// tier (per-chunk compute+store caps peak live regs ~90-110), so this is
// pure added in-flight bytes (128->256 B/lane) at equal occupancy capacity,
// plus halved block churn (2048 blocks). Store discipline kept from R8:
// ALL loads issue before any store, so stores sit behind loads in the vmcnt
// FIFO and chunk-k compute waits retire only loads.
__global__ __launch_bounds__(256) void lcq_kernel(
    const float* __restrict__ x,
    const float* __restrict__ thr,
    const float* __restrict__ theta,
    float* __restrict__ out,
    long long n)
{
    __shared__ float2 s_gb[KB];     // (gamma[j], beta[j])
    __shared__ float  s_pv[KB];     // alpha * expand(m/15)
    __shared__ float  s_scal[2];    // alpha, 1/alpha

    const long long n4ll = n >> 2;
    const vf4* __restrict__ x4 = (const vf4*)x;
    vf4* __restrict__ o4 = (vf4*)out;

    const unsigned base = blockIdx.x * 4096u + threadIdx.x;  // float4 index
    const bool full = ((long long)(blockIdx.x + 1) * 4096ll <= n4ll);

    // ---- (1) issue ALL 16 input loads first (independent of tables) ----
    vf4 v0, v1, v2, v3, v4, v5, v6, v7, v8, v9, v10, v11, v12, v13, v14, v15;
    if (full) {
        v0  = __builtin_nontemporal_load(&x4[base]);
        v1  = __builtin_nontemporal_load(&x4[base +  256u]);
        v2  = __builtin_nontemporal_load(&x4[base +  512u]);
        v3  = __builtin_nontemporal_load(&x4[base +  768u]);
        v4  = __builtin_nontemporal_load(&x4[base + 1024u]);
        v5  = __builtin_nontemporal_load(&x4[base + 1280u]);
        v6  = __builtin_nontemporal_load(&x4[base + 1536u]);
        v7  = __builtin_nontemporal_load(&x4[base + 1792u]);
        v8  = __builtin_nontemporal_load(&x4[base + 2048u]);
        v9  = __builtin_nontemporal_load(&x4[base + 2304u]);
        v10 = __builtin_nontemporal_load(&x4[base + 2560u]);
        v11 = __builtin_nontemporal_load(&x4[base + 2816u]);
        v12 = __builtin_nontemporal_load(&x4[base + 3072u]);
        v13 = __builtin_nontemporal_load(&x4[base + 3328u]);
        v14 = __builtin_nontemporal_load(&x4[base + 3584u]);
        v15 = __builtin_nontemporal_load(&x4[base + 3840u]);
    }

    // ---- (2) table setup overlaps the load latency ----
    if (threadIdx.x == 0) {
        // softmax(theta), fp32, sequential order (bit-matched all rounds)
        float th[KB];
        float mx = theta[0];
        th[0] = mx;
        #pragma unroll
        for (int i = 1; i < KB; ++i) { th[i] = theta[i]; mx = fmaxf(mx, th[i]); }
        float ex[KB];
        float sum = 0.0f;
        #pragma unroll
        for (int i = 0; i < KB; ++i) { ex[i] = expf(__fsub_rn(th[i], mx)); sum = __fadd_rn(sum, ex[i]); }
        float sm[KB];
        #pragma unroll
        for (int i = 0; i < KB; ++i) sm[i] = __fdiv_rn(ex[i], sum);

        float beta[KB], gamma[KB];
        beta[0] = 0.0f;
        float c = sm[0];
        #pragma unroll
        for (int i = 1; i < KB; ++i) { beta[i] = c; c = __fadd_rn(c, sm[i]); }
        #pragma unroll
        for (int i = 0; i < KB; ++i) gamma[i] = __fmul_rn(sm[i], 16.0f);

        #pragma unroll
        for (int i = 0; i < KB; ++i) s_gb[i] = make_float2(gamma[i], beta[i]);

        float alpha = thr[0];
        s_scal[0] = alpha;
        s_scal[1] = __fdiv_rn(1.0f, alpha);  // exact for pow2 alpha (bench: 1.0)

        // pv[m] = alpha * expand(m/15): searchsorted + inverse affine, then
        // the reference's alpha-multiply pre-folded (same operands -> same bits)
        for (int m = 0; m < KB; ++m) {
            float yq = __fdiv_rn((float)m, 15.0f);
            int iq = 0;
            #pragma unroll
            for (int i = 1; i < KB; ++i) iq += (beta[i] <= yq) ? 1 : 0;
            float zv = __fadd_rn(__fdiv_rn(__fsub_rn(yq, beta[iq]), gamma[iq]),
                                 (float)iq * 0.0625f);
            s_pv[m] = __fmul_rn(alpha, zv);
        }
    }
    __syncthreads();   // loads issued ~1200cy ago are landing by the drain

    const float alpha = s_scal[0];
    const float rcpa  = s_scal[1];

    // ---- (3) per-chunk compute + NT store (frees 4 vf4 per chunk; peak
    //          live registers stay in the 65-128 tier) ----
    if (full) {
#define LCQ_CS4(V0, V1, V2, V3, off) { \
        vf4 r0, r1, r2, r3; \
        r0.x = lcq_core(V0.x, alpha, rcpa, s_gb, s_pv); \
        r0.y = lcq_core(V0.y, alpha, rcpa, s_gb, s_pv); \
        r0.z = lcq_core(V0.z, alpha, rcpa, s_gb, s_pv); \
        r0.w = lcq_core(V0.w, alpha, rcpa, s_gb, s_pv); \
        r1.x = lcq_core(V1.x, alpha, rcpa, s_gb, s_pv); \
        r1.y = lcq_core(V1.y, alpha, rcpa, s_gb, s_pv); \
        r1.z = lcq_core(V1.z, alpha, rcpa, s_gb, s_pv); \
        r1.w = lcq_core(V1.w, alpha, rcpa, s_gb, s_pv); \
        r2.x = lcq_core(V2.x, alpha, rcpa, s_gb, s_pv); \
        r2.y = lcq_core(V2.y, alpha, rcpa, s_gb, s_pv); \
        r2.z = lcq_core(V2.z, alpha, rcpa, s_gb, s_pv); \
        r2.w = lcq_core(V2.w, alpha, rcpa, s_gb, s_pv); \
        r3.x = lcq_core(V3.x, alpha, rcpa, s_gb, s_pv); \
        r3.y = lcq_core(V3.y, alpha, rcpa, s_gb, s_pv); \
        r3.z = lcq_core(V3.z, alpha, rcpa, s_gb, s_pv); \
        r3.w = lcq_core(V3.w, alpha, rcpa, s_gb, s_pv); \
        __builtin_nontemporal_store(r0, &o4[base + (off)]); \
        __builtin_nontemporal_store(r1, &o4[base + (off) +  256u]); \
        __builtin_nontemporal_store(r2, &o4[base + (off) +  512u]); \
        __builtin_nontemporal_store(r3, &o4[base + (off) +  768u]); }

        LCQ_CS4(v0,  v1,  v2,  v3,  0u)
        LCQ_CS4(v4,  v5,  v6,  v7,  1024u)
        LCQ_CS4(v8,  v9,  v10, v11, 2048u)
        LCQ_CS4(v12, v13, v14, v15, 3072u)
#undef LCQ_CS4
    } else {
        // Partial last block (not hit at bench shape; kept for generality).
        #pragma unroll
        for (int k = 0; k < 16; ++k) {
            long long i = (long long)base + k * 256;
            if (i < n4ll) {
                vf4 v = x4[i];
                vf4 r;
                r.x = lcq_core(v.x, alpha, rcpa, s_gb, s_pv);
                r.y = lcq_core(v.y, alpha, rcpa, s_gb, s_pv);
                r.z = lcq_core(v.z, alpha, rcpa, s_gb, s_pv);
                r.w = lcq_core(v.w, alpha, rcpa, s_gb, s_pv);
                o4[i] = r;
            }
        }
        // scalar remainder (n % 4), handled by the last block only
        if (blockIdx.x == gridDim.x - 1) {
            for (long long k = (n4ll << 2) + threadIdx.x; k < n; k += 256) {
                out[k] = lcq_core(x[k], alpha, rcpa, s_gb, s_pv);
            }
        }
    }
}

extern "C" void kernel_launch(void* const* d_in, const int* in_sizes, int n_in,
                              void* d_out, int out_size, void* d_ws, size_t ws_size,
                              hipStream_t stream) {
    const float* x     = (const float*)d_in[0];   // (4,4096,2048) fp32
    const float* thr   = (const float*)d_in[1];   // (1,) alpha
    const float* theta = (const float*)d_in[2];   // (16,)
    float* out = (float*)d_out;

    long long n = (long long)in_sizes[0];
    long long n4 = n >> 2;
    long long grid = (n4 + 4095) / 4096;          // bench: 2048 one-shot blocks
    if (grid < 1) grid = 1;
    dim3 block(256);
    hipLaunchKernelGGL(lcq_kernel, dim3((unsigned)grid), block, 0, stream,
                       x, thr, theta, out, n);
}

// Round 10
// 233.859 us; speedup vs baseline: 1.0231x; 1.0231x over previous
//
#include <hip/hip_runtime.h>
#include <math.h>

#define KB 16

// Native clang vector type — required for __builtin_nontemporal_load/store.
typedef float vf4 __attribute__((ext_vector_type(4)));

// Per-element core. Faithful fp32 op order vs reference (__f*_rn blocks FMA
// contraction; rintf == round-half-even == jnp.round). Division by alpha is
// multiply by precomputed 1/alpha — bit-exact for pow2 alpha (bench: 1.0).
// Table holds pv[m] = __fmul_rn(alpha, zval[m]) — bit-identical to the
// reference's final alpha-multiply (R4-R9: absmax 0.0).
__device__ __forceinline__ float lcq_core(float xv, float alpha, float rcp_alpha,
                                          const float2* s_gb,
                                          const float* s_pv)
{
    float a   = fabsf(xv);
    float xt  = __fmul_rn(a, rcp_alpha);            // x_tmp = |x|/alpha
    float t16 = __fmul_rn(xt, 16.0f);               // exact pow2 scale
    float jf  = fminf(t16, 15.0f);
    int   j   = (int)jf;                            // searchsorted(dst,·,right)-1
    float2 gb = s_gb[j];                            // ds_read_b64 (0 conflicts, all rounds)
    float dj  = __fmul_rn(floorf(jf), 0.0625f);     // dst[j] = j/16, exact
    float y   = __fadd_rn(__fmul_rn(gb.x, __fsub_rn(xt, dj)), gb.y);
    float t   = rintf(__fmul_rn(y, 15.0f));         // m = round(y*s), half-even; t>=0
    int   m   = (int)fminf(t, 15.0f);
    float r   = (a < alpha) ? s_pv[m] : alpha;      // flag select, alpha pre-folded
    return copysignf(r, xv);                        // x==0 -> 0 (pv[0]==0)
}

// ROUND 10: break the per-wave serial sum (VALU 29us + mem 42us = 71 ~= the
// measured ~72us kernel). Two serializers found in the R8 champion:
//  (a) lane0's theta loads were VMEM issued AFTER the 8 NT loads — VMEM
//      completes in issue order per wave, so setup waited for ALL data;
//  (b) __syncthreads after setup forces a vmcnt(0) drain — compute always
//      started with ZERO memory in flight.
// Fixes, keeping R8's winning geometry (8 NT loads, 32KB one-shot blocks):
//  (1) theta/thr via uniform loads issued FIRST -> s_load (SMEM, lgkmcnt —
//      independent counter, unordered vs the NT loads' vmcnt);
//  (2) per-wave private tables (4 x 64-float LDS slots, lane0 of each wave
//      builds its own) -> NO __syncthreads anywhere in the kernel;
//  (3) per-chunk compute+store: chunk0 computes at vmcnt(7) while 7 loads
//      are still in flight — first true per-wave VALU/mem overlap.
// MLP lever pinned at 8 loads (R9: 16 loads crossed the 64-VGPR tier, -7us).
__global__ __launch_bounds__(256) void lcq_kernel(
    const float* __restrict__ x,
    const float* __restrict__ thr,
    const float* __restrict__ theta,
    float* __restrict__ out,
    long long n)
{
    __shared__ float s_tab[4][64];  // per-wave slot: [0..31] gb pairs, [32..47] pv

    const long long n4ll = n >> 2;
    const vf4* __restrict__ x4 = (const vf4*)x;
    vf4* __restrict__ o4 = (vf4*)out;

    // ---- (0) uniform loads FIRST: s_load path, lgkmcnt, arrive immediately ----
    float th[KB];
    #pragma unroll
    for (int i = 0; i < KB; ++i) th[i] = theta[i];  // uniform -> SGPR loads
    const float alpha = thr[0];                     // uniform
    const float rcpa  = __fdiv_rn(1.0f, alpha);     // exact for pow2 alpha (bench: 1.0)

    const unsigned base = blockIdx.x * 2048u + threadIdx.x;  // float4 index
    const bool full = ((long long)(blockIdx.x + 1) * 2048ll <= n4ll);

    // ---- (1) issue the 8 NT data loads ----
    vf4 v0, v1, v2, v3, v4, v5, v6, v7;
    if (full) {
        v0 = __builtin_nontemporal_load(&x4[base]);
        v1 = __builtin_nontemporal_load(&x4[base +  256u]);
        v2 = __builtin_nontemporal_load(&x4[base +  512u]);
        v3 = __builtin_nontemporal_load(&x4[base +  768u]);
        v4 = __builtin_nontemporal_load(&x4[base + 1024u]);
        v5 = __builtin_nontemporal_load(&x4[base + 1280u]);
        v6 = __builtin_nontemporal_load(&x4[base + 1536u]);
        v7 = __builtin_nontemporal_load(&x4[base + 1792u]);
    }

    // ---- (2) per-wave table build, lane 0 of each wave; no barrier needed —
    //          LDS writes/reads of one wave are ordered by lgkmcnt, and each
    //          wave touches only its own slot ----
    float* tab = s_tab[threadIdx.x >> 6];
    if ((threadIdx.x & 63) == 0) {
        // softmax(theta), fp32, sequential order (bit-matched all rounds)
        float mx = th[0];
        #pragma unroll
        for (int i = 1; i < KB; ++i) mx = fmaxf(mx, th[i]);
        float ex[KB];
        float sum = 0.0f;
        #pragma unroll
        for (int i = 0; i < KB; ++i) { ex[i] = expf(__fsub_rn(th[i], mx)); sum = __fadd_rn(sum, ex[i]); }
        float sm[KB];
        #pragma unroll
        for (int i = 0; i < KB; ++i) sm[i] = __fdiv_rn(ex[i], sum);

        float beta[KB], gamma[KB];
        beta[0] = 0.0f;
        float c = sm[0];
        #pragma unroll
        for (int i = 1; i < KB; ++i) { beta[i] = c; c = __fadd_rn(c, sm[i]); }
        #pragma unroll
        for (int i = 0; i < KB; ++i) gamma[i] = __fmul_rn(sm[i], 16.0f);

        #pragma unroll
        for (int i = 0; i < KB; ++i) ((float2*)tab)[i] = make_float2(gamma[i], beta[i]);

        // pv[m] = alpha * expand(m/15): searchsorted + inverse affine, then
        // the reference's alpha-multiply pre-folded (same operands -> same bits)
        for (int m = 0; m < KB; ++m) {
            float yq = __fdiv_rn((float)m, 15.0f);
            int iq = 0;
            #pragma unroll
            for (int i = 1; i < KB; ++i) iq += (beta[i] <= yq) ? 1 : 0;
            float zv = __fadd_rn(__fdiv_rn(__fsub_rn(yq, beta[iq]), gamma[iq]),
                                 (float)iq * 0.0625f);
            tab[32 + m] = __fmul_rn(alpha, zv);
        }
    }
    const float2* gbp = (const float2*)tab;
    const float*  pvp = tab + 32;

    // ---- (3) per-chunk compute + NT store: chunk k's compute waits only on
    //          its own load (descending vmcnt); stores are younger VMEM and
    //          never block subsequent load-consumption ----
    if (full) {
#define LCQ_CS(V, off) { \
        vf4 r; \
        r.x = lcq_core(V.x, alpha, rcpa, gbp, pvp); \
        r.y = lcq_core(V.y, alpha, rcpa, gbp, pvp); \
        r.z = lcq_core(V.z, alpha, rcpa, gbp, pvp); \
        r.w = lcq_core(V.w, alpha, rcpa, gbp, pvp); \
        __builtin_nontemporal_store(r, &o4[base + (off)]); }
        LCQ_CS(v0, 0u)
        LCQ_CS(v1, 256u)
        LCQ_CS(v2, 512u)
        LCQ_CS(v3, 768u)
        LCQ_CS(v4, 1024u)
        LCQ_CS(v5, 1280u)
        LCQ_CS(v6, 1536u)
        LCQ_CS(v7, 1792u)
#undef LCQ_CS
    } else {
        // Partial last block (not hit at bench shape; kept for generality).
        #pragma unroll
        for (int k = 0; k < 8; ++k) {
            long long i = (long long)base + k * 256;
            if (i < n4ll) {
                vf4 v = x4[i];
                vf4 r;
                r.x = lcq_core(v.x, alpha, rcpa, gbp, pvp);
                r.y = lcq_core(v.y, alpha, rcpa, gbp, pvp);
                r.z = lcq_core(v.z, alpha, rcpa, gbp, pvp);
                r.w = lcq_core(v.w, alpha, rcpa, gbp, pvp);
                o4[i] = r;
            }
        }
        // scalar remainder (n % 4), handled by the last block only
        if (blockIdx.x == gridDim.x - 1) {
            for (long long k = (n4ll << 2) + threadIdx.x; k < n; k += 256) {
                out[k] = lcq_core(x[k], alpha, rcpa, gbp, pvp);
            }
        }
    }
}

extern "C" void kernel_launch(void* const* d_in, const int* in_sizes, int n_in,
                              void* d_out, int out_size, void* d_ws, size_t ws_size,
                              hipStream_t stream) {
    const float* x     = (const float*)d_in[0];   // (4,4096,2048) fp32
    const float* thr   = (const float*)d_in[1];   // (1,) alpha
    const float* theta = (const float*)d_in[2];   // (16,)
    float* out = (float*)d_out;

    long long n = (long long)in_sizes[0];
    long long n4 = n >> 2;
    long long grid = (n4 + 2047) / 2048;          // bench: 4096 one-shot blocks
    if (grid < 1) grid = 1;
    dim3 block(256);
    hipLaunchKernelGGL(lcq_kernel, dim3((unsigned)grid), block, 0, stream,
                       x, thr, theta, out, n);
}